// Round 12
// baseline (153.355 us; speedup 1.0000x reference)
//
#include <hip/hip_runtime.h>

#define LREL(x) ((x) > 0.0f ? (x) : 0.2f * (x))
#define TILE1 6250   // dsts per tile; 8 tiles cover N=50000
#define SLICES 16
#define NT 8         // tiles
#define PB 256       // partition-build blocks

// Precompute reduced projection weights pw[32][12] and bias-through term bk[2].
__global__ void k_precomp(const float* __restrict__ W1, const float* __restrict__ aL1,
                          const float* __restrict__ aR1, const float* __restrict__ W2,
                          const float* __restrict__ b1, float* __restrict__ pw,
                          float* __restrict__ bk) {
    int tid = threadIdx.x;
    if (tid < 384) {
        int k = tid / 12, q = tid % 12;
        float acc = 0.f;
        if (q < 2) {
            int h = q;
#pragma unroll
            for (int o = 0; o < 64; ++o) acc = fmaf(W1[k * 128 + h * 64 + o], aL1[h * 64 + o], acc);
        } else if (q < 4) {
            int h = q - 2;
#pragma unroll
            for (int o = 0; o < 64; ++o) acc = fmaf(W1[k * 128 + h * 64 + o], aR1[h * 64 + o], acc);
        } else {
            int r = q - 4;
            int rel = r >> 2, h = (r >> 1) & 1, kk = r & 1;
#pragma unroll
            for (int o = 0; o < 64; ++o)
                acc = fmaf(W1[k * 128 + h * 64 + o], W2[(rel * 128 + h * 64 + o) * 2 + kk], acc);
        }
        pw[k * 12 + q] = acc;
    } else if (tid < 386) {
        int k = tid - 384;
        float acc = 0.f;
#pragma unroll
        for (int c = 0; c < 256; ++c) acc = fmaf(b1[c & 127], W2[c * 2 + k], acc);
        bk[k] = acc;
    }
}

// Collapsed layer-1 projection: [N,32] x [32,12] -> el1 [N,2], er1 [N,2], g [N,8].
__global__ void k_proj(const float* __restrict__ x, const float* __restrict__ pw,
                       float* __restrict__ el1, float* __restrict__ er1,
                       float* __restrict__ g, int N) {
    __shared__ float ps[384];
    for (int i = threadIdx.x; i < 384; i += 256) ps[i] = pw[i];
    __syncthreads();
    int n = blockIdx.x * 256 + threadIdx.x;
    if (n >= N) return;
    float xr[32];
#pragma unroll
    for (int u = 0; u < 8; ++u) {
        float4 v = *(const float4*)(x + (long)n * 32 + u * 4);
        xr[u * 4 + 0] = v.x; xr[u * 4 + 1] = v.y;
        xr[u * 4 + 2] = v.z; xr[u * 4 + 3] = v.w;
    }
    float o[12];
#pragma unroll
    for (int q = 0; q < 12; ++q) o[q] = 0.f;
#pragma unroll
    for (int k = 0; k < 32; ++k) {
        float xv = xr[k];
#pragma unroll
        for (int q = 0; q < 12; ++q) o[q] = fmaf(xv, ps[k * 12 + q], o[q]);
    }
    *(float2*)(el1 + 2 * n) = make_float2(o[0], o[1]);
    *(float2*)(er1 + 2 * n) = make_float2(o[2], o[3]);
    *(float4*)(g + (long)n * 8)     = make_float4(o[4], o[5], o[6], o[7]);
    *(float4*)(g + (long)n * 8 + 4) = make_float4(o[8], o[9], o[10], o[11]);
}

// Partition histogram: cnt[p*PB + b] = #edges of block b's chunk in partition p
// (p = rel*8 + tile). 16 lane-subcounters per partition kill LDS contention.
__global__ void k_count(const int* __restrict__ dstF, const int* __restrict__ dstL,
                        int* __restrict__ cnt, int E) {
    __shared__ int h[16][16];
    int tid = threadIdx.x, b = blockIdx.x;
    ((int*)h)[tid] = 0;
    __syncthreads();
    int chunk = (E + PB - 1) / PB;
    int lo = b * chunk, hi = lo + chunk; if (hi > E) hi = E;
    int sub = tid & 15;
    for (int e = lo + tid; e < hi; e += 256) {
        atomicAdd(&h[dstF[e] / TILE1][sub], 1);
        atomicAdd(&h[8 + dstL[e] / TILE1][sub], 1);
    }
    __syncthreads();
    if (tid < 16) {
        int s = 0;
#pragma unroll
        for (int k = 0; k < 16; ++k) s += h[tid][k];
        cnt[tid * PB + b] = s;
    }
}

// Exclusive scan of the 4096 (p,block) counts -> off[0..4096].
__global__ void k_pscan(const int* __restrict__ cnt, int* __restrict__ off) {
    __shared__ int ls[1024];
    int tid = threadIdx.x;
    int4 v = *(const int4*)(cnt + tid * 4);
    int s = v.x + v.y + v.z + v.w;
    ls[tid] = s;
    __syncthreads();
    for (int o = 1; o < 1024; o <<= 1) {
        int t = (tid >= o) ? ls[tid - o] : 0;
        __syncthreads();
        ls[tid] += t;
        __syncthreads();
    }
    int run = ls[tid] - s;  // exclusive
    off[tid * 4 + 0] = run; run += v.x;
    off[tid * 4 + 1] = run; run += v.y;
    off[tid * 4 + 2] = run; run += v.z;
    off[tid * 4 + 3] = run; run += v.w;
    if (tid == 1023) off[4096] = run;  // = 2E
}

// Write packed edges (src<<13 | dst_local) into partition arrays. Block-local LDS
// cursors -> per-wave slot runs are ~consecutive (low write amplification).
__global__ void k_pwrite(const int* __restrict__ srcF, const int* __restrict__ dstF,
                         const int* __restrict__ srcL, const int* __restrict__ dstL,
                         const int* __restrict__ off, int* __restrict__ part, int E) {
    __shared__ int cur[16];
    int tid = threadIdx.x, b = blockIdx.x;
    if (tid < 16) cur[tid] = off[tid * PB + b];
    __syncthreads();
    int chunk = (E + PB - 1) / PB;
    int lo = b * chunk, hi = lo + chunk; if (hi > E) hi = E;
    for (int e = lo + tid; e < hi; e += 256) {
        int s = srcF[e], d = dstF[e];
        int t = d / TILE1, dl = d - t * TILE1;
        int slot = atomicAdd(&cur[t], 1);
        part[slot] = (s << 13) | dl;
        s = srcL[e]; d = dstL[e];
        t = d / TILE1; dl = d - t * TILE1;
        slot = atomicAdd(&cur[8 + t], 1);
        part[slot] = (s << 13) | dl;
    }
}

// Layer-1 aggregation over a partition slice: 100% hit rate, 4 B/edge.
__global__ __launch_bounds__(1024) void k_agg1p(
        const int* __restrict__ part, const int* __restrict__ off,
        const float* __restrict__ el1, const float* __restrict__ er1,
        const float* __restrict__ g, float* __restrict__ partial1, int E2) {
    __shared__ float bins[TILE1 * 6];  // 150,000 B
    int s = blockIdx.x, t = blockIdx.y, rel = blockIdx.z;
    int p = rel * 8 + t;
    int start = off[p * PB], end = (p == 15) ? E2 : off[(p + 1) * PB];
    for (int i = threadIdx.x; i < TILE1 * 6 / 4; i += blockDim.x)
        ((float4*)bins)[i] = make_float4(0.f, 0.f, 0.f, 0.f);
    __syncthreads();
    int len = end - start;
    int sl = (len + SLICES - 1) / SLICES;
    int j0 = start + s * sl;
    int j1 = j0 + sl; if (j1 > end) j1 = end; if (j0 > end) j0 = end;
    int base = t * TILE1;
    for (int j = j0 + threadIdx.x; j < j1; j += blockDim.x) {
        int px = part[j];
        int dl = px & 8191, sn = px >> 13;
        float2 els = *(const float2*)(el1 + 2 * sn);
        float2 erd = *(const float2*)(er1 + 2 * (base + dl));
        float4 gv = *(const float4*)(g + (long)sn * 8 + rel * 4);
        float w0 = __expf(LREL(els.x + erd.x));
        float w1 = __expf(LREL(els.y + erd.y));
        float* bb = bins + dl * 6;
        atomicAdd(bb + 0, w0 * gv.x);
        atomicAdd(bb + 1, w0 * gv.y);
        atomicAdd(bb + 2, w1 * gv.z);
        atomicAdd(bb + 3, w1 * gv.w);
        atomicAdd(bb + 4, w0);
        atomicAdd(bb + 5, w1);
    }
    __syncthreads();
    float* dstp = partial1 + (((long)rel * NT + t) * SLICES + s) * (TILE1 * 6);
    for (int i = threadIdx.x; i < TILE1 * 6 / 4; i += blockDim.x)
        ((float4*)dstp)[i] = ((const float4*)bins)[i];
}

// Merge layer-1 partials over slices; combine (rel,h) into h2[d,0:2].
__global__ void k_merge1(const float* __restrict__ partial1, const float* __restrict__ bk,
                         float* __restrict__ h2, int N) {
    int d = blockIdx.x * blockDim.x + threadIdx.x;
    if (d >= N) return;
    int t = d / TILE1, dl = d % TILE1;
    float r0 = bk[0], r1 = bk[1];
#pragma unroll
    for (int rel = 0; rel < 2; ++rel) {
        const float* p = partial1 + (((long)rel * NT + t) * SLICES) * (TILE1 * 6) + (long)dl * 6;
        float n00 = 0.f, n01 = 0.f, n10 = 0.f, n11 = 0.f, w0 = 0.f, w1 = 0.f;
        for (int s = 0; s < SLICES; ++s) {
            const float* q = p + (long)s * (TILE1 * 6);
            float2 a = *(const float2*)(q + 0);
            float2 b = *(const float2*)(q + 2);
            float2 c = *(const float2*)(q + 4);
            n00 += a.x; n01 += a.y;
            n10 += b.x; n11 += b.y;
            w0  += c.x; w1  += c.y;
        }
        if (w0 > 0.f) { r0 += n00 / w0; r1 += n01 / w0; }
        if (w1 > 0.f) { r0 += n10 / w1; r1 += n11 / w1; }
    }
    *(float2*)(h2 + 2 * d) = make_float2(r0, r1);
}

// Layer-2 aggregation over the same partitions: bins[dl][4] = {n0, n1, w0s, w1s}.
__global__ __launch_bounds__(1024) void k_agg2p(
        const int* __restrict__ part, const int* __restrict__ off,
        const float* __restrict__ h2, const float* __restrict__ aL2,
        const float* __restrict__ aR2, float* __restrict__ partial2, int E2) {
    __shared__ float bins[TILE1 * 4];  // 100,000 B
    int s = blockIdx.x, t = blockIdx.y, rel = blockIdx.z;
    int p = rel * 8 + t;
    int start = off[p * PB], end = (p == 15) ? E2 : off[(p + 1) * PB];
    float aL0 = aL2[0], aL1_ = aL2[1], aR0 = aR2[0], aR1_ = aR2[1];
    for (int i = threadIdx.x; i < TILE1; i += blockDim.x)
        ((float4*)bins)[i] = make_float4(0.f, 0.f, 0.f, 0.f);
    __syncthreads();
    int len = end - start;
    int sl = (len + SLICES - 1) / SLICES;
    int j0 = start + s * sl;
    int j1 = j0 + sl; if (j1 > end) j1 = end; if (j0 > end) j0 = end;
    int base = t * TILE1;
    for (int j = j0 + threadIdx.x; j < j1; j += blockDim.x) {
        int px = part[j];
        int dl = px & 8191, sn = px >> 13;
        float2 hs = *(const float2*)(h2 + 2 * sn);
        float2 hd = *(const float2*)(h2 + 2 * (base + dl));
        float w0 = __expf(LREL(hs.x * aL0 + hd.x * aR0));
        float w1 = __expf(LREL(hs.y * aL1_ + hd.y * aR1_));
        float* bb = bins + dl * 4;
        atomicAdd(bb + 0, w0 * hs.x);
        atomicAdd(bb + 1, w1 * hs.y);
        atomicAdd(bb + 2, w0);
        atomicAdd(bb + 3, w1);
    }
    __syncthreads();
    float* dstp = partial2 + (((long)rel * NT + t) * SLICES + s) * (TILE1 * 4);
    for (int i = threadIdx.x; i < TILE1; i += blockDim.x)
        ((float4*)dstp)[i] = ((const float4*)bins)[i];
}

// Merge layer-2 partials; final out[d, rel*2+h] = n_h/w_h + b2[h].
__global__ void k_merge2(const float* __restrict__ partial2, const float* __restrict__ b2,
                         float* __restrict__ out, int N) {
    int d = blockIdx.x * blockDim.x + threadIdx.x;
    if (d >= N) return;
    int t = d / TILE1, dl = d % TILE1;
    float b20 = b2[0], b21 = b2[1];
    float4 o;
#pragma unroll
    for (int rel = 0; rel < 2; ++rel) {
        const float* p = partial2 + (((long)rel * NT + t) * SLICES) * (TILE1 * 4) + (long)dl * 4;
        float n0 = 0.f, n1 = 0.f, w0 = 0.f, w1 = 0.f;
        for (int s = 0; s < SLICES; ++s) {
            float4 q = *(const float4*)(p + (long)s * (TILE1 * 4));
            n0 += q.x; n1 += q.y; w0 += q.z; w1 += q.w;
        }
        float o0 = (w0 > 0.f ? n0 / w0 : 0.f) + b20;
        float o1 = (w1 > 0.f ? n1 / w1 : 0.f) + b21;
        if (rel == 0) { o.x = o0; o.y = o1; } else { o.z = o0; o.w = o1; }
    }
    *(float4*)(out + (long)d * 4) = o;
}

extern "C" void kernel_launch(void* const* d_in, const int* in_sizes, int n_in,
                              void* d_out, int out_size, void* d_ws, size_t ws_size,
                              hipStream_t stream) {
    const float* x   = (const float*)d_in[0];
    const float* W1  = (const float*)d_in[1];
    const float* aL1 = (const float*)d_in[2];
    const float* aR1 = (const float*)d_in[3];
    const float* b1  = (const float*)d_in[4];
    const float* W2  = (const float*)d_in[5];
    const float* aL2 = (const float*)d_in[6];
    const float* aR2 = (const float*)d_in[7];
    const float* b2  = (const float*)d_in[8];
    const int* srcF  = (const int*)d_in[9];
    const int* dstF  = (const int*)d_in[10];
    const int* srcL  = (const int*)d_in[11];
    const int* dstL  = (const int*)d_in[12];
    float* out = (float*)d_out;

    const int N = in_sizes[0] / 32;
    const int E = in_sizes[9];

    // Workspace: g 8N | el1 2N | er1 2N | h2 2N | partial1 | partial2 | bk | pw | part 2E | cnt | off
    float* ws   = (float*)d_ws;
    float* g    = ws;                              // 8N
    float* el1  = g + (long)8 * N;                 // 2N
    float* er1  = el1 + (long)2 * N;               // 2N
    float* h2   = er1 + (long)2 * N;               // 2N
    float* partial1 = h2 + (long)2 * N;            // 2*8*16*TILE1*6 = 9.6M floats
    float* partial2 = partial1 + (long)2 * NT * SLICES * TILE1 * 6;  // 6.4M floats
    float* bk   = partial2 + (long)2 * NT * SLICES * TILE1 * 4;      // 16
    float* pw   = bk + 16;                         // 384
    int* part   = (int*)(pw + 384);                // 2E
    int* cnt    = part + (long)2 * E;              // 4096
    int* off    = cnt + 4096;                      // 4097
    // total ~= 73.3 MB (<= 81 MB proven in round 2)

    k_precomp<<<1, 512, 0, stream>>>(W1, aL1, aR1, W2, b1, pw, bk);
    k_proj<<<(N + 255) / 256, 256, 0, stream>>>(x, pw, el1, er1, g, N);

    k_count<<<PB, 256, 0, stream>>>(dstF, dstL, cnt, E);
    k_pscan<<<1, 1024, 0, stream>>>(cnt, off);
    k_pwrite<<<PB, 256, 0, stream>>>(srcF, dstF, srcL, dstL, off, part, E);

    dim3 agrid(SLICES, NT, 2);
    k_agg1p<<<agrid, 1024, 0, stream>>>(part, off, el1, er1, g, partial1, 2 * E);
    k_merge1<<<(N + 255) / 256, 256, 0, stream>>>(partial1, bk, h2, N);
    k_agg2p<<<agrid, 1024, 0, stream>>>(part, off, h2, aL2, aR2, partial2, 2 * E);
    k_merge2<<<(N + 255) / 256, 256, 0, stream>>>(partial2, b2, out, N);
}

// Round 13
// 146.929 us; speedup vs baseline: 1.0437x; 1.0437x over previous
//
#include <hip/hip_runtime.h>

#define LREL(x) ((x) > 0.0f ? (x) : 0.2f * (x))
#define TILE 1568    // dsts per tile; 32 tiles cover N=50000 (dl fits 11 bits)
#define NT 32
#define SLICES 8
#define PB 256       // partition-build blocks
#define ST1 7        // layer-1 bin stride (floats): gcd(7,32)=1 -> all 32 banks
#define ST2 5        // layer-2 bin stride: gcd(5,32)=1

// Precompute reduced projection weights pw[32][12] and bias-through term bk[2].
__global__ void k_precomp(const float* __restrict__ W1, const float* __restrict__ aL1,
                          const float* __restrict__ aR1, const float* __restrict__ W2,
                          const float* __restrict__ b1, float* __restrict__ pw,
                          float* __restrict__ bk) {
    int tid = threadIdx.x;
    if (tid < 384) {
        int k = tid / 12, q = tid % 12;
        float acc = 0.f;
        if (q < 2) {
            int h = q;
#pragma unroll
            for (int o = 0; o < 64; ++o) acc = fmaf(W1[k * 128 + h * 64 + o], aL1[h * 64 + o], acc);
        } else if (q < 4) {
            int h = q - 2;
#pragma unroll
            for (int o = 0; o < 64; ++o) acc = fmaf(W1[k * 128 + h * 64 + o], aR1[h * 64 + o], acc);
        } else {
            int r = q - 4;
            int rel = r >> 2, h = (r >> 1) & 1, kk = r & 1;
#pragma unroll
            for (int o = 0; o < 64; ++o)
                acc = fmaf(W1[k * 128 + h * 64 + o], W2[(rel * 128 + h * 64 + o) * 2 + kk], acc);
        }
        pw[k * 12 + q] = acc;
    } else if (tid < 386) {
        int k = tid - 384;
        float acc = 0.f;
#pragma unroll
        for (int c = 0; c < 256; ++c) acc = fmaf(b1[c & 127], W2[c * 2 + k], acc);
        bk[k] = acc;
    }
}

// Collapsed layer-1 projection: [N,32] x [32,12] -> el1 [N,2], er1 [N,2], g [N,8].
__global__ void k_proj(const float* __restrict__ x, const float* __restrict__ pw,
                       float* __restrict__ el1, float* __restrict__ er1,
                       float* __restrict__ g, int N) {
    __shared__ float ps[384];
    for (int i = threadIdx.x; i < 384; i += 256) ps[i] = pw[i];
    __syncthreads();
    int n = blockIdx.x * 256 + threadIdx.x;
    if (n >= N) return;
    float xr[32];
#pragma unroll
    for (int u = 0; u < 8; ++u) {
        float4 v = *(const float4*)(x + (long)n * 32 + u * 4);
        xr[u * 4 + 0] = v.x; xr[u * 4 + 1] = v.y;
        xr[u * 4 + 2] = v.z; xr[u * 4 + 3] = v.w;
    }
    float o[12];
#pragma unroll
    for (int q = 0; q < 12; ++q) o[q] = 0.f;
#pragma unroll
    for (int k = 0; k < 32; ++k) {
        float xv = xr[k];
#pragma unroll
        for (int q = 0; q < 12; ++q) o[q] = fmaf(xv, ps[k * 12 + q], o[q]);
    }
    *(float2*)(el1 + 2 * n) = make_float2(o[0], o[1]);
    *(float2*)(er1 + 2 * n) = make_float2(o[2], o[3]);
    *(float4*)(g + (long)n * 8)     = make_float4(o[4], o[5], o[6], o[7]);
    *(float4*)(g + (long)n * 8 + 4) = make_float4(o[8], o[9], o[10], o[11]);
}

// Partition histogram: cnt[p*PB + b], p = rel*32 + tile (64 partitions).
__global__ void k_count(const int* __restrict__ dstF, const int* __restrict__ dstL,
                        int* __restrict__ cnt, int E) {
    __shared__ int h[64][16];
    int tid = threadIdx.x, b = blockIdx.x;
    for (int i = tid; i < 64 * 16; i += 256) ((int*)h)[i] = 0;
    __syncthreads();
    int chunk = (E + PB - 1) / PB;
    int lo = b * chunk, hi = lo + chunk; if (hi > E) hi = E;
    int sub = tid & 15;
    for (int e = lo + tid; e < hi; e += 256) {
        atomicAdd(&h[dstF[e] / TILE][sub], 1);
        atomicAdd(&h[32 + dstL[e] / TILE][sub], 1);
    }
    __syncthreads();
    if (tid < 64) {
        int s = 0;
#pragma unroll
        for (int k = 0; k < 16; ++k) s += h[tid][k];
        cnt[tid * PB + b] = s;
    }
}

// Exclusive scan of 16384 (p,block) counts -> off[0..16384].
__global__ void k_pscan(const int* __restrict__ cnt, int* __restrict__ off) {
    __shared__ int ls[1024];
    int tid = threadIdx.x;
    int v[16];
    int s = 0;
#pragma unroll
    for (int u = 0; u < 4; ++u) {
        int4 q = *(const int4*)(cnt + tid * 16 + u * 4);
        v[u * 4 + 0] = q.x; v[u * 4 + 1] = q.y; v[u * 4 + 2] = q.z; v[u * 4 + 3] = q.w;
        s += q.x + q.y + q.z + q.w;
    }
    ls[tid] = s;
    __syncthreads();
    for (int o = 1; o < 1024; o <<= 1) {
        int t = (tid >= o) ? ls[tid - o] : 0;
        __syncthreads();
        ls[tid] += t;
        __syncthreads();
    }
    int run = ls[tid] - s;  // exclusive prefix
#pragma unroll
    for (int u = 0; u < 16; ++u) { off[tid * 16 + u] = run; run += v[u]; }
    if (tid == 1023) off[16384] = run;  // = 2E
}

// Write packed edges (src<<11 | dst_local) into partitions via block-local LDS cursors.
__global__ void k_pwrite(const int* __restrict__ srcF, const int* __restrict__ dstF,
                         const int* __restrict__ srcL, const int* __restrict__ dstL,
                         const int* __restrict__ off, int* __restrict__ part, int E) {
    __shared__ int cur[64];
    int tid = threadIdx.x, b = blockIdx.x;
    if (tid < 64) cur[tid] = off[tid * PB + b];
    __syncthreads();
    int chunk = (E + PB - 1) / PB;
    int lo = b * chunk, hi = lo + chunk; if (hi > E) hi = E;
    for (int e = lo + tid; e < hi; e += 256) {
        int s = srcF[e], d = dstF[e];
        int t = d / TILE, dl = d - t * TILE;
        int slot = atomicAdd(&cur[t], 1);
        part[slot] = (s << 11) | dl;
        s = srcL[e]; d = dstL[e];
        t = d / TILE; dl = d - t * TILE;
        slot = atomicAdd(&cur[32 + t], 1);
        part[slot] = (s << 11) | dl;
    }
}

// Layer-1 aggregation: bins stride 7 (all 32 banks). 256 thr; 512-block grid.
__global__ __launch_bounds__(256) void k_agg1p(
        const int* __restrict__ part, const int* __restrict__ off,
        const float* __restrict__ el1, const float* __restrict__ er1,
        const float* __restrict__ g, float* __restrict__ partial1) {
    __shared__ float bins[TILE * ST1];  // 43,904 B
    int s = blockIdx.x, t = blockIdx.y, rel = blockIdx.z;
    int p = rel * 32 + t;
    int start = off[p * PB], end = off[(p + 1) * PB];
    for (int i = threadIdx.x; i < TILE * ST1 / 4; i += 256)
        ((float4*)bins)[i] = make_float4(0.f, 0.f, 0.f, 0.f);
    __syncthreads();
    int len = end - start;
    int sl = (len + SLICES - 1) / SLICES;
    int j0 = start + s * sl;
    int j1 = j0 + sl; if (j1 > end) j1 = end; if (j0 > end) j0 = end;
    int base = t * TILE;
    for (int j = j0 + threadIdx.x; j < j1; j += 256) {
        int px = part[j];
        int dl = px & 2047, sn = px >> 11;
        float2 els = *(const float2*)(el1 + 2 * sn);
        float2 erd = *(const float2*)(er1 + 2 * (base + dl));
        float4 gv = *(const float4*)(g + (long)sn * 8 + rel * 4);
        float w0 = __expf(LREL(els.x + erd.x));
        float w1 = __expf(LREL(els.y + erd.y));
        float* bb = bins + dl * ST1;
        atomicAdd(bb + 0, w0 * gv.x);
        atomicAdd(bb + 1, w0 * gv.y);
        atomicAdd(bb + 2, w1 * gv.z);
        atomicAdd(bb + 3, w1 * gv.w);
        atomicAdd(bb + 4, w0);
        atomicAdd(bb + 5, w1);
    }
    __syncthreads();
    float* dstp = partial1 + (((long)rel * NT + t) * SLICES + s) * (TILE * ST1);
    for (int i = threadIdx.x; i < TILE * ST1 / 4; i += 256)
        ((float4*)dstp)[i] = ((const float4*)bins)[i];
}

// Merge layer-1 partials over slices; combine (rel,h) into h2[d,0:2].
__global__ void k_merge1(const float* __restrict__ partial1, const float* __restrict__ bk,
                         float* __restrict__ h2, int N) {
    int d = blockIdx.x * blockDim.x + threadIdx.x;
    if (d >= N) return;
    int t = d / TILE, dl = d % TILE;
    float r0 = bk[0], r1 = bk[1];
#pragma unroll
    for (int rel = 0; rel < 2; ++rel) {
        const float* p = partial1 + (((long)rel * NT + t) * SLICES) * (TILE * ST1) + (long)dl * ST1;
        float n00 = 0.f, n01 = 0.f, n10 = 0.f, n11 = 0.f, w0 = 0.f, w1 = 0.f;
        for (int s = 0; s < SLICES; ++s) {
            const float* q = p + (long)s * (TILE * ST1);
            n00 += q[0]; n01 += q[1];
            n10 += q[2]; n11 += q[3];
            w0  += q[4]; w1  += q[5];
        }
        if (w0 > 0.f) { r0 += n00 / w0; r1 += n01 / w0; }
        if (w1 > 0.f) { r0 += n10 / w1; r1 += n11 / w1; }
    }
    *(float2*)(h2 + 2 * d) = make_float2(r0, r1);
}

// Layer-2 aggregation: bins stride 5 = {n0, n1, w0s, w1s, pad}.
__global__ __launch_bounds__(256) void k_agg2p(
        const int* __restrict__ part, const int* __restrict__ off,
        const float* __restrict__ h2, const float* __restrict__ aL2,
        const float* __restrict__ aR2, float* __restrict__ partial2) {
    __shared__ float bins[TILE * ST2];  // 31,360 B
    int s = blockIdx.x, t = blockIdx.y, rel = blockIdx.z;
    int p = rel * 32 + t;
    int start = off[p * PB], end = off[(p + 1) * PB];
    float aL0 = aL2[0], aL1_ = aL2[1], aR0 = aR2[0], aR1_ = aR2[1];
    for (int i = threadIdx.x; i < TILE * ST2 / 4; i += 256)
        ((float4*)bins)[i] = make_float4(0.f, 0.f, 0.f, 0.f);
    __syncthreads();
    int len = end - start;
    int sl = (len + SLICES - 1) / SLICES;
    int j0 = start + s * sl;
    int j1 = j0 + sl; if (j1 > end) j1 = end; if (j0 > end) j0 = end;
    int base = t * TILE;
    for (int j = j0 + threadIdx.x; j < j1; j += 256) {
        int px = part[j];
        int dl = px & 2047, sn = px >> 11;
        float2 hs = *(const float2*)(h2 + 2 * sn);
        float2 hd = *(const float2*)(h2 + 2 * (base + dl));
        float w0 = __expf(LREL(hs.x * aL0 + hd.x * aR0));
        float w1 = __expf(LREL(hs.y * aL1_ + hd.y * aR1_));
        float* bb = bins + dl * ST2;
        atomicAdd(bb + 0, w0 * hs.x);
        atomicAdd(bb + 1, w1 * hs.y);
        atomicAdd(bb + 2, w0);
        atomicAdd(bb + 3, w1);
    }
    __syncthreads();
    float* dstp = partial2 + (((long)rel * NT + t) * SLICES + s) * (TILE * ST2);
    for (int i = threadIdx.x; i < TILE * ST2 / 4; i += 256)
        ((float4*)dstp)[i] = ((const float4*)bins)[i];
}

// Merge layer-2 partials; final out[d, rel*2+h] = n_h/w_h + b2[h].
__global__ void k_merge2(const float* __restrict__ partial2, const float* __restrict__ b2,
                         float* __restrict__ out, int N) {
    int d = blockIdx.x * blockDim.x + threadIdx.x;
    if (d >= N) return;
    int t = d / TILE, dl = d % TILE;
    float b20 = b2[0], b21 = b2[1];
    float4 o;
#pragma unroll
    for (int rel = 0; rel < 2; ++rel) {
        const float* p = partial2 + (((long)rel * NT + t) * SLICES) * (TILE * ST2) + (long)dl * ST2;
        float n0 = 0.f, n1 = 0.f, w0 = 0.f, w1 = 0.f;
        for (int s = 0; s < SLICES; ++s) {
            const float* q = p + (long)s * (TILE * ST2);
            n0 += q[0]; n1 += q[1]; w0 += q[2]; w1 += q[3];
        }
        float o0 = (w0 > 0.f ? n0 / w0 : 0.f) + b20;
        float o1 = (w1 > 0.f ? n1 / w1 : 0.f) + b21;
        if (rel == 0) { o.x = o0; o.y = o1; } else { o.z = o0; o.w = o1; }
    }
    *(float4*)(out + (long)d * 4) = o;
}

extern "C" void kernel_launch(void* const* d_in, const int* in_sizes, int n_in,
                              void* d_out, int out_size, void* d_ws, size_t ws_size,
                              hipStream_t stream) {
    const float* x   = (const float*)d_in[0];
    const float* W1  = (const float*)d_in[1];
    const float* aL1 = (const float*)d_in[2];
    const float* aR1 = (const float*)d_in[3];
    const float* b1  = (const float*)d_in[4];
    const float* W2  = (const float*)d_in[5];
    const float* aL2 = (const float*)d_in[6];
    const float* aR2 = (const float*)d_in[7];
    const float* b2  = (const float*)d_in[8];
    const int* srcF  = (const int*)d_in[9];
    const int* dstF  = (const int*)d_in[10];
    const int* srcL  = (const int*)d_in[11];
    const int* dstL  = (const int*)d_in[12];
    float* out = (float*)d_out;

    const int N = in_sizes[0] / 32;
    const int E = in_sizes[9];

    // Workspace layout
    float* ws   = (float*)d_ws;
    float* g    = ws;                              // 8N
    float* el1  = g + (long)8 * N;                 // 2N
    float* er1  = el1 + (long)2 * N;               // 2N
    float* h2   = er1 + (long)2 * N;               // 2N
    float* partial1 = h2 + (long)2 * N;            // 2*NT*SLICES*TILE*ST1 = 5.62M floats
    float* partial2 = partial1 + (long)2 * NT * SLICES * TILE * ST1;  // 4.01M floats
    float* bk   = partial2 + (long)2 * NT * SLICES * TILE * ST2;      // 16
    float* pw   = bk + 16;                         // 384
    int* part   = (int*)(pw + 384);                // 2E
    int* cnt    = part + (long)2 * E;              // 16384
    int* off    = cnt + 16384;                     // 16385
    // total ~= 48 MB (<= 81 MB proven in round 2)

    k_precomp<<<1, 512, 0, stream>>>(W1, aL1, aR1, W2, b1, pw, bk);
    k_proj<<<(N + 255) / 256, 256, 0, stream>>>(x, pw, el1, er1, g, N);

    k_count<<<PB, 256, 0, stream>>>(dstF, dstL, cnt, E);
    k_pscan<<<1, 1024, 0, stream>>>(cnt, off);
    k_pwrite<<<PB, 256, 0, stream>>>(srcF, dstF, srcL, dstL, off, part, E);

    dim3 agrid(SLICES, NT, 2);
    k_agg1p<<<agrid, 256, 0, stream>>>(part, off, el1, er1, g, partial1);
    k_merge1<<<(N + 255) / 256, 256, 0, stream>>>(partial1, bk, h2, N);
    k_agg2p<<<agrid, 256, 0, stream>>>(part, off, h2, aL2, aR2, partial2);
    k_merge2<<<(N + 255) / 256, 256, 0, stream>>>(partial2, b2, out, N);
}